// Round 2
// baseline (304.530 us; speedup 1.0000x reference)
//
#include <hip/hip_runtime.h>
#include <hip/hip_fp16.h>

// GCN, fp16 chain + MFMA GEMMs + direct-scatter adjacency build.
//   R12: replace bin(512-bucket LDS histogram)+bucket(counting sort) with a
//   ONE-pass fixed-stride direct scatter: r=atomicAdd(&cnt[d],1);
//   slots[d*72+r]=src. Kills k_bucket, the binned+csr round-trip (21MB),
//   offs, and the dis array (dis = rsqrtf(cnt+1) computed where needed --
//   every consumer already loads cnt or can; random dis[idx] load becomes
//   random cnt[idx] load, same traffic).
//   Pipeline: memset(cnt) -> [scatter || gemm1] -> gather1 -> gemm2 -> gather2.
//   h1  = fp16(x@W1)  UNSCALED  [fused with scatter; MFMA 16x16x32_f16]
//   a1  = fp16(relu(b1 + ds_d*(ds_d*h1[d] + sum ds_s*h1[s])))  [gather, f32 acc]
//   h2' = fp16((a1@W2)*ds) -> gather w/ fused @Wfc+bfc (fp32 out)
// Lessons held: no E-scale LDS fp32 atomics (R10: 1550us), shfl only in
// wave-uniform exec (R5), gather at per-request latency floor ~57us
// (R7/R8/R9 bounced), CSR build passes are the cost -- minimize them (R11).

#define CAP  72      // slots per node: mean deg 16, sigma 4 -> +14 sigma
#define SCB  512     // scatter blocks in fused grid (before gemm blocks)

typedef float v2f __attribute__((ext_vector_type(2)));
typedef _Float16 f16x8 __attribute__((ext_vector_type(8)));
typedef float f32x4 __attribute__((ext_vector_type(4)));

// Fused dispatch: blocks [0,SCB) direct-scatter edges into per-node slot
// rows; blocks [SCB, SCB+gb) compute h1 = fp16(x@W1) UNSCALED (normalization
// folded into gather1). Independent dataflow -> complementary pipes overlap.
__global__ __launch_bounds__(256) void k_scat_gemm1(
        const int* __restrict__ src, const int* __restrict__ dst, int e,
        int* __restrict__ cnt, int* __restrict__ slots,
        const float* __restrict__ X, const float* __restrict__ W1,
        __half* __restrict__ Hh, int n) {
    __shared__ _Float16 As[128 * 136];
    __shared__ _Float16 Bs[64 * 136];

    int t = threadIdx.x;

    if (blockIdx.x < SCB) {
        // ---------------- direct scatter ----------------
        int i0 = blockIdx.x * 256 + t;
        int stride = SCB * 256;
        for (int i = i0; i < e; i += stride) {
            int d = dst[i];
            int s = src[i];
            int r = atomicAdd(&cnt[d], 1);
            if (r < CAP)                       // never at +14 sigma
                slots[(size_t)d * CAP + r] = s;
        }
    } else {
        // ---------------- gemm1 (K=128, f32 input, UNSCALED out) ----------------
        constexpr int K = 128, KP = 136;
        _Float16* H = (_Float16*)Hh;

        // stage Bs: inline transpose W1 [128][64] f32 -> Bs[nn][k] fp16
        #pragma unroll
        for (int p = 0; p < 8; ++p) {            // 2048 float4 / 256 thr
            int i = t + p * 256;
            int k = i >> 4, nn4 = (i & 15) << 2;
            float4 v = ((const float4*)W1)[i];
            Bs[(nn4 + 0) * KP + k] = (_Float16)v.x;
            Bs[(nn4 + 1) * KP + k] = (_Float16)v.y;
            Bs[(nn4 + 2) * KP + k] = (_Float16)v.z;
            Bs[(nn4 + 3) * KP + k] = (_Float16)v.w;
        }

        int row0 = (blockIdx.x - SCB) * 128;
        #pragma unroll
        for (int p = 0; p < 8; ++p) {            // 128 rows x 16 segs
            int gi  = t + p * 256;
            int row = gi >> 4, sg = gi & 15;
            int grow = row0 + row;
            float4 v0 = make_float4(0.f, 0.f, 0.f, 0.f), v1 = v0;
            if (grow < n) {
                v0 = *(const float4*)(X + (size_t)grow * K + sg * 8);
                v1 = *(const float4*)(X + (size_t)grow * K + sg * 8 + 4);
            }
            union { __half2 h[4]; float4 f; } u;
            u.h[0] = __floats2half2_rn(v0.x, v0.y);
            u.h[1] = __floats2half2_rn(v0.z, v0.w);
            u.h[2] = __floats2half2_rn(v1.x, v1.y);
            u.h[3] = __floats2half2_rn(v1.z, v1.w);
            *(float4*)(As + row * KP + sg * 8) = u.f;
        }
        __syncthreads();

        int wv   = t >> 6;
        int lane = t & 63;
        int m    = lane & 15;
        int quad = lane >> 4;
        int r0   = wv * 32;

        f32x4 acc[2][4] = {};
        #pragma unroll
        for (int kb = 0; kb < K / 32; ++kb) {
            f16x8 af0 = *(const f16x8*)(As + (r0 + m) * KP + quad * 8 + kb * 32);
            f16x8 af1 = *(const f16x8*)(As + (r0 + 16 + m) * KP + quad * 8 + kb * 32);
            #pragma unroll
            for (int nt = 0; nt < 4; ++nt) {
                f16x8 bf = *(const f16x8*)(Bs + (nt * 16 + m) * KP + quad * 8 + kb * 32);
                acc[0][nt] = __builtin_amdgcn_mfma_f32_16x16x32_f16(af0, bf, acc[0][nt], 0, 0, 0);
                acc[1][nt] = __builtin_amdgcn_mfma_f32_16x16x32_f16(af1, bf, acc[1][nt], 0, 0, 0);
            }
        }

        // D: col = lane&15, row = quad*4 + reg  [m89-verified]; no dis scale
        #pragma unroll
        for (int mt = 0; mt < 2; ++mt) {
            int gr[4];
            #pragma unroll
            for (int r = 0; r < 4; ++r)
                gr[r] = row0 + r0 + mt * 16 + quad * 4 + r;
            #pragma unroll
            for (int nt = 0; nt < 4; ++nt)
                #pragma unroll
                for (int r = 0; r < 4; ++r) {
                    if (gr[r] < n)
                        H[(size_t)gr[r] * 64 + nt * 16 + m] =
                            (_Float16)acc[mt][nt][r];
                    else if (gr[r] == n)   // zero mask-row for the gather
                        H[(size_t)n * 64 + nt * 16 + m] = (_Float16)0.f;
                }
        }
    }
}

// MFMA GEMM, layer 2: A1[n,64] fp16 @ W2 (inline-transposed fp16) ->
// H[row][col] = fp16(acc * rsqrt(cnt[row]+1)).
__global__ __launch_bounds__(256) void k_gemm2(const __half* __restrict__ X,
                                               const float* __restrict__ W2,
                                               const int* __restrict__ cnt,
                                               __half* __restrict__ Hh, int n) {
    constexpr int K = 64, KP = 72;
    __shared__ _Float16 As[128 * KP];
    __shared__ _Float16 Bs[64 * KP];

    int t = threadIdx.x;
    _Float16* H = (_Float16*)Hh;

    // stage Bs: inline transpose W2 [64][64] f32 -> Bs[nn][k] fp16
    #pragma unroll
    for (int p = 0; p < 4; ++p) {               // 1024 float4 / 256 thr
        int i = t + p * 256;
        int k = i >> 4, nn4 = (i & 15) << 2;
        float4 v = ((const float4*)W2)[i];
        Bs[(nn4 + 0) * KP + k] = (_Float16)v.x;
        Bs[(nn4 + 1) * KP + k] = (_Float16)v.y;
        Bs[(nn4 + 2) * KP + k] = (_Float16)v.z;
        Bs[(nn4 + 3) * KP + k] = (_Float16)v.w;
    }

    int row0 = blockIdx.x * 128;
    const __half* Xh = X;
    #pragma unroll
    for (int p = 0; p < 4; ++p) {               // 128 rows x 8 segs
        int gi  = t + p * 256;
        int row = gi >> 3, sg = gi & 7;
        int grow = row0 + row;
        float4 v = make_float4(0.f, 0.f, 0.f, 0.f);
        if (grow < n)
            v = *(const float4*)(Xh + (size_t)grow * K + sg * 8);
        *(float4*)(As + row * KP + sg * 8) = v;
    }
    __syncthreads();

    int wv   = t >> 6;
    int lane = t & 63;
    int m    = lane & 15;
    int quad = lane >> 4;
    int r0   = wv * 32;

    f32x4 acc[2][4] = {};
    #pragma unroll
    for (int kb = 0; kb < K / 32; ++kb) {
        f16x8 af0 = *(const f16x8*)(As + (r0 + m) * KP + quad * 8 + kb * 32);
        f16x8 af1 = *(const f16x8*)(As + (r0 + 16 + m) * KP + quad * 8 + kb * 32);
        #pragma unroll
        for (int nt = 0; nt < 4; ++nt) {
            f16x8 bf = *(const f16x8*)(Bs + (nt * 16 + m) * KP + quad * 8 + kb * 32);
            acc[0][nt] = __builtin_amdgcn_mfma_f32_16x16x32_f16(af0, bf, acc[0][nt], 0, 0, 0);
            acc[1][nt] = __builtin_amdgcn_mfma_f32_16x16x32_f16(af1, bf, acc[1][nt], 0, 0, 0);
        }
    }

    #pragma unroll
    for (int mt = 0; mt < 2; ++mt) {
        float dv[4]; int gr[4];
        #pragma unroll
        for (int r = 0; r < 4; ++r) {
            gr[r] = row0 + r0 + mt * 16 + quad * 4 + r;
            dv[r] = (gr[r] < n) ? rsqrtf((float)(cnt[gr[r]] + 1)) : 0.f;
        }
        #pragma unroll
        for (int nt = 0; nt < 4; ++nt)
            #pragma unroll
            for (int r = 0; r < 4; ++r) {
                if (gr[r] < n)
                    H[(size_t)gr[r] * 64 + nt * 16 + m] =
                        (_Float16)(acc[mt][nt][r] * dv[r]);
                else if (gr[r] == n)
                    H[(size_t)n * 64 + nt * 16 + m] = (_Float16)0.f;
            }
    }
}

__device__ inline void add_row(const __half* __restrict__ hp, int s, int c4,
                               v2f& lo, v2f& hi) {
    float2 raw = *(const float2*)(hp + (size_t)s * 64 + c4);   // 4 halves
    const __half2* p = (const __half2*)&raw;
    float2 l = __half22float2(p[0]);
    float2 h = __half22float2(p[1]);
    lo += (v2f){ l.x, l.y };
    hi += (v2f){ h.x, h.y };
}

__device__ inline void fma_row(const __half* __restrict__ hp, int s, int c4,
                               float w, v2f& lo, v2f& hi) {
    float2 raw = *(const float2*)(hp + (size_t)s * 64 + c4);   // 4 halves
    const __half2* p = (const __half2*)&raw;
    float2 l = __half22float2(p[0]);
    float2 h = __half22float2(p[1]);
    lo += w * (v2f){ l.x, l.y };
    hi += w * (v2f){ h.x, h.y };
}

// Wave per node: 4 edges x 16 lanes x 4 fp16 channels, fp32 accumulation.
// Slot row is fixed-stride (start = d*CAP, contiguous 256B read of <=64 idx).
// Degrees -> norms on the fly: ds = rsqrtf(cnt+1); per-source cnt[idx] is
// the same random 4B load dis[idx] used to be.
// SCALE=true: hp rows are UNSCALED h1; weight each row by ds[src].
// FUSE=false: out is fp16 [n,64] (feeds MFMA GEMM2). FUSE=true: fp32 [n,4].
template<bool FUSE, bool SCALE>
__global__ __launch_bounds__(256) void k_gather(const __half* __restrict__ hp,
                                                const int* __restrict__ slots,
                                                const int* __restrict__ cnt,
                                                const float* __restrict__ bias,
                                                void* __restrict__ outb,
                                                const float* __restrict__ Wfc,
                                                const float* __restrict__ bfc,
                                                int n) {
    int lane = threadIdx.x & 63;
    int wid  = (blockIdx.x * blockDim.x + threadIdx.x) >> 6;
    if (wid >= n) return;                      // wave-uniform (wave per node)
    int d    = wid;
    int esub = lane >> 4;
    int c4   = (lane & 15) * 4;

    size_t start = (size_t)d * CAP;
    int num  = cnt[d];
    int numc = min(num, CAP);
    int lim  = min(numc, 64);
    int idx  = (lane < lim) ? slots[start + lane] : 0;
    float dsv = 0.f;
    if constexpr (SCALE) {
        int cv = cnt[idx];                     // per-src degree, prefetched
        dsv = rsqrtf((float)(cv + 1));
    }
    float dd = rsqrtf((float)(num + 1));       // self degree incl. self-loop

    v2f aL[4] = {}, aH[4] = {};
    if (esub == 0) {                           // self-loop
        if constexpr (SCALE) fma_row(hp, d, c4, dd, aL[0], aH[0]);
        else                 add_row(hp, d, c4, aL[0], aH[0]);
    }

    int j = 0;
    for (; j + 16 <= lim; j += 16) {           // full batches: no clamp needed
        int s0 = __shfl(idx, j + esub);
        int s1 = __shfl(idx, j + 4 + esub);
        int s2 = __shfl(idx, j + 8 + esub);
        int s3 = __shfl(idx, j + 12 + esub);
        if constexpr (SCALE) {
            float w0 = __shfl(dsv, j + esub);
            float w1 = __shfl(dsv, j + 4 + esub);
            float w2 = __shfl(dsv, j + 8 + esub);
            float w3 = __shfl(dsv, j + 12 + esub);
            fma_row(hp, s0, c4, w0, aL[0], aH[0]);
            fma_row(hp, s1, c4, w1, aL[1], aH[1]);
            fma_row(hp, s2, c4, w2, aL[2], aH[2]);
            fma_row(hp, s3, c4, w3, aL[3], aH[3]);
        } else {
            add_row(hp, s0, c4, aL[0], aH[0]);
            add_row(hp, s1, c4, aL[1], aH[1]);
            add_row(hp, s2, c4, aL[2], aH[2]);
            add_row(hp, s3, c4, aL[3], aH[3]);
        }
    }
    for (; j < lim; j += 4) {                  // tail: clamp pads to zero row
        int jj = j + esub;                     // jj <= 63 here
        int sr = __shfl(idx, jj);              // uniform exec
        int s  = (jj < lim) ? sr : n;          // zero row at index n
        if constexpr (SCALE) {
            float w = __shfl(dsv, jj);         // w*0 = 0 on padded rows
            fma_row(hp, s, c4, w, aL[0], aH[0]);
        } else {
            add_row(hp, s, c4, aL[0], aH[0]);
        }
    }
    for (int j2 = 64; j2 < numc; j2 += 4) {    // deg>64: essentially never
        int jj = j2 + esub;
        if (jj < numc) {
            int s = slots[start + jj];         // direct load, no shfl
            if constexpr (SCALE) {
                float w = rsqrtf((float)(cnt[s] + 1));
                fma_row(hp, s, c4, w, aL[1], aH[1]);
            } else {
                add_row(hp, s, c4, aL[1], aH[1]);
            }
        }
    }
    v2f sL = (aL[0] + aL[1]) + (aL[2] + aL[3]);
    v2f sH = (aH[0] + aH[1]) + (aH[2] + aH[3]);
    float4 a0 = make_float4(sL.x, sL.y, sH.x, sH.y);
    #pragma unroll
    for (int o = 16; o <= 32; o <<= 1) {
        a0.x += __shfl_xor(a0.x, o);
        a0.y += __shfl_xor(a0.y, o);
        a0.z += __shfl_xor(a0.z, o);
        a0.w += __shfl_xor(a0.w, o);
    }
    float4 bb = *(const float4*)(bias + c4);
    float4 o;
    o.x = fmaxf(bb.x + dd * a0.x, 0.f);
    o.y = fmaxf(bb.y + dd * a0.y, 0.f);
    o.z = fmaxf(bb.z + dd * a0.z, 0.f);
    o.w = fmaxf(bb.w + dd * a0.w, 0.f);
    if (!FUSE) {
        if (esub == 0) {
            union { __half2 h[2]; float2 f; } u;
            u.h[0] = __floats2half2_rn(o.x, o.y);
            u.h[1] = __floats2half2_rn(o.z, o.w);
            *(float2*)((__half*)outb + (size_t)d * 64 + c4) = u.f;
        }
    } else {
        const float4* W4 = (const float4*)Wfc;   // row r -> Wfc[r][0..3]
        float4 w0 = W4[c4 + 0], w1 = W4[c4 + 1], w2 = W4[c4 + 2], w3 = W4[c4 + 3];
        float4 p;
        p.x = o.x * w0.x + o.y * w1.x + o.z * w2.x + o.w * w3.x;
        p.y = o.x * w0.y + o.y * w1.y + o.z * w2.y + o.w * w3.y;
        p.z = o.x * w0.z + o.y * w1.z + o.z * w2.z + o.w * w3.z;
        p.w = o.x * w0.w + o.y * w1.w + o.z * w2.w + o.w * w3.w;
        #pragma unroll
        for (int q = 1; q <= 8; q <<= 1) {
            p.x += __shfl_xor(p.x, q);
            p.y += __shfl_xor(p.y, q);
            p.z += __shfl_xor(p.z, q);
            p.w += __shfl_xor(p.w, q);
        }
        if (lane == 0) {
            float4 bf = *(const float4*)bfc;
            float4 r = make_float4(p.x + bf.x, p.y + bf.y, p.z + bf.z, p.w + bf.w);
            ((float4*)outb)[d] = r;
        }
    }
}

static inline size_t align256(size_t x) { return (x + 255) & ~(size_t)255; }

extern "C" void kernel_launch(void* const* d_in, const int* in_sizes, int n_in,
                              void* d_out, int out_size, void* d_ws, size_t ws_size,
                              hipStream_t stream) {
    const float* x   = (const float*)d_in[0];
    const int*   ei  = (const int*)d_in[1];
    const float* W1  = (const float*)d_in[2];
    const float* b1  = (const float*)d_in[3];
    const float* W2  = (const float*)d_in[4];
    const float* b2  = (const float*)d_in[5];
    const float* Wfc = (const float*)d_in[6];
    const float* bfc = (const float*)d_in[7];
    float* out = (float*)d_out;

    int n = in_sizes[0] / 128;   // 100000
    int e = in_sizes[1] / 2;     // 1600000
    const int* src = ei;
    const int* dst = ei + e;

    char* ws = (char*)d_ws;
    size_t p = 0;
    int*    cnt   = (int*)   (ws + p); p = align256(p + (size_t)n * 4);
    int*    slots = (int*)   (ws + p); p = align256(p + (size_t)n * CAP * 4);
    __half* hbuf  = (__half*)(ws + p); p = align256(p + (size_t)(n + 1) * 64 * 2);
    __half* a1h   = (__half*)(ws + p);           // n*64 fp16

    int gb = (n + 127) / 128;        // 782 gemm tiles (last covers row n)

    // zero degree counters, then fused direct-scatter + gemm1 (scatter blocks
    // first in grid -> resident immediately; gemm blocks backfill).
    hipMemsetAsync(cnt, 0, (size_t)n * sizeof(int), stream);
    k_scat_gemm1<<<SCB + gb, 256, 0, stream>>>(src, dst, e, cnt, slots,
                                               x, W1, hbuf, n);

    // layer 1 aggregate: a1 = relu(b1 + ds*(ds*h1[d] + sum ds_s*h1[s]))
    k_gather<false, true><<<(n * 64 + 255) / 256, 256, 0, stream>>>(
        hbuf, slots, cnt, b1, a1h, nullptr, nullptr, n);

    // layer 2: h2' (fp16, MFMA, scaled, reuses hbuf) -> fused final projection
    k_gemm2<<<gb, 256, 0, stream>>>(a1h, W2, cnt, hbuf, n);
    k_gather<true, false><<<(n * 64 + 255) / 256, 256, 0, stream>>>(
        hbuf, slots, cnt, b2, out, Wfc, bfc, n);
}

// Round 3
// 253.347 us; speedup vs baseline: 1.2020x; 1.2020x over previous
//
#include <hip/hip_runtime.h>
#include <hip/hip_fp16.h>

// GCN, fp16 chain + MFMA GEMMs + two-phase packed CSR build.
//   R13: keep R11's [bin || gemm1] fusion + packed binned runs, but replace
//   k_bucket's counting sort (prefix scan, 16 barrier rounds, 3 LDS passes)
//   with k_bucket2: atomic rank IS the slot index. Per-node LDS lists
//   (stride 33: copy-out at fixed r would hit one bank at stride 32),
//   overflow (r>=32, ~4sigma) direct to global, single barrier, packed
//   copy-out into line-aligned slots[d*64]. No scan, no dis array, no
//   n-word memset (bucket2 writes every cnt[d]).
//   Pipeline: memset(bcur,2KB) -> [bin || gemm1] -> bucket2 -> gather1
//             -> gemm2 -> gather2.
//   h1  = fp16(x@W1)  UNSCALED  [fused with bin; MFMA 16x16x32_f16]
//   a1  = fp16(relu(b1 + ds_d*(ds_d*h1[d] + sum ds_s*h1[s])))  [gather, f32]
//   h2' = fp16((a1@W2)*ds) -> gather w/ fused @Wfc+bfc (fp32 out)
// Lessons held: no E-scale LDS fp32 atomics (R10: 1550us); shfl only in
// wave-uniform exec (R5); gather at per-request latency floor ~57us
// (R7/R8/R9 bounced); direct per-node GLOBAL scatter = 16x write
// amplification, 109MB writes, 114us (R12) -- pack through LDS first.

#define BCAP 5120    // binned slots per 256-node bucket (+16 sigma)
#define BINB 512     // bin portion of fused grid
#define CHUNK 3200   // >= ceil(E / BINB) = 3125
#define CAP  64      // slots per node (line-aligned rows; +12 sigma, ~4e-18)
#define LCAP 32      // LDS list cap per node; overflow direct-global

typedef float v2f __attribute__((ext_vector_type(2)));
typedef _Float16 f16x8 __attribute__((ext_vector_type(8)));
typedef float f32x4 __attribute__((ext_vector_type(4)));

// Fused dispatch: blocks [0, BINB) partition edges into fixed-capacity
// bucket segments of packed u32 (src<<8 | ldst); blocks [BINB, BINB+gb)
// compute h1 = fp16(x@W1) UNSCALED (normalization folded into gather1).
__global__ __launch_bounds__(256) void k_bin_gemm1(
        const int* __restrict__ src, const int* __restrict__ dst, int e,
        int* bcur, unsigned* __restrict__ binned,
        const float* __restrict__ X, const float* __restrict__ W1,
        __half* __restrict__ Hh, int n) {
    __shared__ union {
        struct {
            unsigned ec[CHUNK];          // packed src<<8|ldst
            unsigned short eb[CHUNK];    // bucket id
            int lh[512], lbase[512], lr[512];
        } b;
        struct {
            _Float16 As[128 * 136];
            _Float16 Bs[64 * 136];
        } g;
    } sm;

    int t = threadIdx.x;

    if (blockIdx.x < BINB) {
        // ---------------- bin ----------------
        unsigned* ec = sm.b.ec;
        unsigned short* eb = sm.b.eb;
        int* lh = sm.b.lh; int* lbase = sm.b.lbase; int* lr = sm.b.lr;
        for (int i = t; i < 512; i += 256) { lh[i] = 0; lr[i] = 0; }
        __syncthreads();
        int chunk = (e + BINB - 1) / BINB;   // 3125 <= CHUNK
        int lo = blockIdx.x * chunk;
        int hi = min(e, lo + chunk);
        for (int i = lo + t; i < hi; i += 256) {
            int d = dst[i];
            int b = d >> 8;
            ec[i - lo] = ((unsigned)src[i] << 8) | (unsigned)(d & 255);
            eb[i - lo] = (unsigned short)b;
            atomicAdd(&lh[b], 1);
        }
        __syncthreads();
        for (int i = t; i < 512; i += 256)
            lbase[i] = lh[i] ? atomicAdd(&bcur[i], lh[i]) : 0;
        __syncthreads();
        int cnt = hi - lo;
        for (int i = t; i < cnt; i += 256) {
            int b = eb[i];
            int r = lbase[b] + atomicAdd(&lr[b], 1);
            if (r < BCAP)                   // overflow guard (never at 16 sigma)
                binned[(size_t)b * BCAP + r] = ec[i];
        }
    } else {
        // ---------------- gemm1 (K=128, f32 input, UNSCALED out) ----------------
        constexpr int K = 128, KP = 136;
        _Float16* As = sm.g.As;
        _Float16* Bs = sm.g.Bs;
        _Float16* H = (_Float16*)Hh;

        // stage Bs: inline transpose W1 [128][64] f32 -> Bs[nn][k] fp16
        #pragma unroll
        for (int p = 0; p < 8; ++p) {            // 2048 float4 / 256 thr
            int i = t + p * 256;
            int k = i >> 4, nn4 = (i & 15) << 2;
            float4 v = ((const float4*)W1)[i];
            Bs[(nn4 + 0) * KP + k] = (_Float16)v.x;
            Bs[(nn4 + 1) * KP + k] = (_Float16)v.y;
            Bs[(nn4 + 2) * KP + k] = (_Float16)v.z;
            Bs[(nn4 + 3) * KP + k] = (_Float16)v.w;
        }

        int row0 = (blockIdx.x - BINB) * 128;
        #pragma unroll
        for (int p = 0; p < 8; ++p) {            // 128 rows x 16 segs
            int gi  = t + p * 256;
            int row = gi >> 4, sg = gi & 15;
            int grow = row0 + row;
            float4 v0 = make_float4(0.f, 0.f, 0.f, 0.f), v1 = v0;
            if (grow < n) {
                v0 = *(const float4*)(X + (size_t)grow * K + sg * 8);
                v1 = *(const float4*)(X + (size_t)grow * K + sg * 8 + 4);
            }
            union { __half2 h[4]; float4 f; } u;
            u.h[0] = __floats2half2_rn(v0.x, v0.y);
            u.h[1] = __floats2half2_rn(v0.z, v0.w);
            u.h[2] = __floats2half2_rn(v1.x, v1.y);
            u.h[3] = __floats2half2_rn(v1.z, v1.w);
            *(float4*)(As + row * KP + sg * 8) = u.f;
        }
        __syncthreads();

        int wv   = t >> 6;
        int lane = t & 63;
        int m    = lane & 15;
        int quad = lane >> 4;
        int r0   = wv * 32;

        f32x4 acc[2][4] = {};
        #pragma unroll
        for (int kb = 0; kb < K / 32; ++kb) {
            f16x8 af0 = *(const f16x8*)(As + (r0 + m) * KP + quad * 8 + kb * 32);
            f16x8 af1 = *(const f16x8*)(As + (r0 + 16 + m) * KP + quad * 8 + kb * 32);
            #pragma unroll
            for (int nt = 0; nt < 4; ++nt) {
                f16x8 bf = *(const f16x8*)(Bs + (nt * 16 + m) * KP + quad * 8 + kb * 32);
                acc[0][nt] = __builtin_amdgcn_mfma_f32_16x16x32_f16(af0, bf, acc[0][nt], 0, 0, 0);
                acc[1][nt] = __builtin_amdgcn_mfma_f32_16x16x32_f16(af1, bf, acc[1][nt], 0, 0, 0);
            }
        }

        // D: col = lane&15, row = quad*4 + reg  [m89-verified]; no dis scale
        #pragma unroll
        for (int mt = 0; mt < 2; ++mt) {
            int gr[4];
            #pragma unroll
            for (int r = 0; r < 4; ++r)
                gr[r] = row0 + r0 + mt * 16 + quad * 4 + r;
            #pragma unroll
            for (int nt = 0; nt < 4; ++nt)
                #pragma unroll
                for (int r = 0; r < 4; ++r) {
                    if (gr[r] < n)
                        H[(size_t)gr[r] * 64 + nt * 16 + m] =
                            (_Float16)acc[mt][nt][r];
                    else if (gr[r] == n)   // zero mask-row for the gather
                        H[(size_t)n * 64 + nt * 16 + m] = (_Float16)0.f;
                }
        }
    }
}

// One block per 256-node bucket: the atomic rank IS the slot index.
// LDS per-node lists (stride 33: at fixed r, stride-32 would put all 64
// lanes of the copy-out on one bank), overflow direct to global (rare),
// packed copy-out into line-aligned slots rows. No scan, 2 barriers.
__global__ __launch_bounds__(256) void k_bucket2(const unsigned* __restrict__ binned,
                                                 const int* __restrict__ bcur,
                                                 int n, int* __restrict__ cnt,
                                                 int* __restrict__ slots) {
    __shared__ int lists[256 * (LCAP + 1)];
    __shared__ int lcnt[256];
    int b = blockIdx.x, t = threadIdx.x;
    int node0 = b << 8;
    size_t ebase = (size_t)b * BCAP;
    int ecnt = min(bcur[b], BCAP);
    lcnt[t] = 0;
    __syncthreads();
    for (int j = t; j < ecnt; j += 256) {
        unsigned ed = binned[ebase + j];
        int ld = ed & 255u;
        int s  = (int)(ed >> 8);
        int r  = atomicAdd(&lcnt[ld], 1);
        if (r < LCAP)
            lists[ld * (LCAP + 1) + r] = s;
        else if (r < CAP)                   // ~4-sigma tail: direct global
            slots[((size_t)(node0 + ld) << 6) + r] = s;
    }
    __syncthreads();
    int d = node0 + t;
    if (d < n) {
        int c = lcnt[t];
        cnt[d] = c;
        int m = min(c, LCAP);
        size_t base = (size_t)d << 6;
        for (int r = 0; r < m; ++r)
            slots[base + r] = lists[t * (LCAP + 1) + r];
    }
}

// MFMA GEMM, layer 2: A1[n,64] fp16 @ W2 (inline-transposed fp16) ->
// H[row][col] = fp16(acc * rsqrt(cnt[row]+1)).
__global__ __launch_bounds__(256) void k_gemm2(const __half* __restrict__ X,
                                               const float* __restrict__ W2,
                                               const int* __restrict__ cnt,
                                               __half* __restrict__ Hh, int n) {
    constexpr int K = 64, KP = 72;
    __shared__ _Float16 As[128 * KP];
    __shared__ _Float16 Bs[64 * KP];

    int t = threadIdx.x;
    _Float16* H = (_Float16*)Hh;

    // stage Bs: inline transpose W2 [64][64] f32 -> Bs[nn][k] fp16
    #pragma unroll
    for (int p = 0; p < 4; ++p) {               // 1024 float4 / 256 thr
        int i = t + p * 256;
        int k = i >> 4, nn4 = (i & 15) << 2;
        float4 v = ((const float4*)W2)[i];
        Bs[(nn4 + 0) * KP + k] = (_Float16)v.x;
        Bs[(nn4 + 1) * KP + k] = (_Float16)v.y;
        Bs[(nn4 + 2) * KP + k] = (_Float16)v.z;
        Bs[(nn4 + 3) * KP + k] = (_Float16)v.w;
    }

    int row0 = blockIdx.x * 128;
    const __half* Xh = X;
    #pragma unroll
    for (int p = 0; p < 4; ++p) {               // 128 rows x 8 segs
        int gi  = t + p * 256;
        int row = gi >> 3, sg = gi & 7;
        int grow = row0 + row;
        float4 v = make_float4(0.f, 0.f, 0.f, 0.f);
        if (grow < n)
            v = *(const float4*)(Xh + (size_t)grow * K + sg * 8);
        *(float4*)(As + row * KP + sg * 8) = v;
    }
    __syncthreads();

    int wv   = t >> 6;
    int lane = t & 63;
    int m    = lane & 15;
    int quad = lane >> 4;
    int r0   = wv * 32;

    f32x4 acc[2][4] = {};
    #pragma unroll
    for (int kb = 0; kb < K / 32; ++kb) {
        f16x8 af0 = *(const f16x8*)(As + (r0 + m) * KP + quad * 8 + kb * 32);
        f16x8 af1 = *(const f16x8*)(As + (r0 + 16 + m) * KP + quad * 8 + kb * 32);
        #pragma unroll
        for (int nt = 0; nt < 4; ++nt) {
            f16x8 bf = *(const f16x8*)(Bs + (nt * 16 + m) * KP + quad * 8 + kb * 32);
            acc[0][nt] = __builtin_amdgcn_mfma_f32_16x16x32_f16(af0, bf, acc[0][nt], 0, 0, 0);
            acc[1][nt] = __builtin_amdgcn_mfma_f32_16x16x32_f16(af1, bf, acc[1][nt], 0, 0, 0);
        }
    }

    #pragma unroll
    for (int mt = 0; mt < 2; ++mt) {
        float dv[4]; int gr[4];
        #pragma unroll
        for (int r = 0; r < 4; ++r) {
            gr[r] = row0 + r0 + mt * 16 + quad * 4 + r;
            dv[r] = (gr[r] < n) ? rsqrtf((float)(cnt[gr[r]] + 1)) : 0.f;
        }
        #pragma unroll
        for (int nt = 0; nt < 4; ++nt)
            #pragma unroll
            for (int r = 0; r < 4; ++r) {
                if (gr[r] < n)
                    H[(size_t)gr[r] * 64 + nt * 16 + m] =
                        (_Float16)(acc[mt][nt][r] * dv[r]);
                else if (gr[r] == n)
                    H[(size_t)n * 64 + nt * 16 + m] = (_Float16)0.f;
            }
    }
}

__device__ inline void add_row(const __half* __restrict__ hp, int s, int c4,
                               v2f& lo, v2f& hi) {
    float2 raw = *(const float2*)(hp + (size_t)s * 64 + c4);   // 4 halves
    const __half2* p = (const __half2*)&raw;
    float2 l = __half22float2(p[0]);
    float2 h = __half22float2(p[1]);
    lo += (v2f){ l.x, l.y };
    hi += (v2f){ h.x, h.y };
}

__device__ inline void fma_row(const __half* __restrict__ hp, int s, int c4,
                               float w, v2f& lo, v2f& hi) {
    float2 raw = *(const float2*)(hp + (size_t)s * 64 + c4);   // 4 halves
    const __half2* p = (const __half2*)&raw;
    float2 l = __half22float2(p[0]);
    float2 h = __half22float2(p[1]);
    lo += w * (v2f){ l.x, l.y };
    hi += w * (v2f){ h.x, h.y };
}

// Wave per node: 4 edges x 16 lanes x 4 fp16 channels, fp32 accumulation.
// Slot rows are line-aligned (d<<6): the <=64 idx load is one coalesced
// 256B read. Norms on the fly: ds = rsqrtf(cnt+1); per-src cnt[idx] is the
// same random 4B load dis[idx] used to be (cnt is 400KB, L2-resident).
// SCALE=true: hp rows are UNSCALED h1; weight each row by ds[src].
// FUSE=false: out is fp16 [n,64] (feeds MFMA GEMM2). FUSE=true: fp32 [n,4].
template<bool FUSE, bool SCALE>
__global__ __launch_bounds__(256) void k_gather(const __half* __restrict__ hp,
                                                const int* __restrict__ slots,
                                                const int* __restrict__ cnt,
                                                const float* __restrict__ bias,
                                                void* __restrict__ outb,
                                                const float* __restrict__ Wfc,
                                                const float* __restrict__ bfc,
                                                int n) {
    int lane = threadIdx.x & 63;
    int wid  = (blockIdx.x * blockDim.x + threadIdx.x) >> 6;
    if (wid >= n) return;                      // wave-uniform (wave per node)
    int d    = wid;
    int esub = lane >> 4;
    int c4   = (lane & 15) * 4;

    size_t start = (size_t)d << 6;
    int num = cnt[d];
    int lim = min(num, CAP);                   // CAP=64: no tail loop needed
    int idx = (lane < lim) ? slots[start + lane] : 0;
    float dsv = 0.f;
    if constexpr (SCALE)
        dsv = rsqrtf((float)(cnt[idx] + 1));   // per-src norm, prefetched
    float dd = rsqrtf((float)(num + 1));       // self degree incl. self-loop

    v2f aL[4] = {}, aH[4] = {};
    if (esub == 0) {                           // self-loop
        if constexpr (SCALE) fma_row(hp, d, c4, dd, aL[0], aH[0]);
        else                 add_row(hp, d, c4, aL[0], aH[0]);
    }

    int j = 0;
    for (; j + 16 <= lim; j += 16) {           // full batches: no clamp needed
        int s0 = __shfl(idx, j + esub);
        int s1 = __shfl(idx, j + 4 + esub);
        int s2 = __shfl(idx, j + 8 + esub);
        int s3 = __shfl(idx, j + 12 + esub);
        if constexpr (SCALE) {
            float w0 = __shfl(dsv, j + esub);
            float w1 = __shfl(dsv, j + 4 + esub);
            float w2 = __shfl(dsv, j + 8 + esub);
            float w3 = __shfl(dsv, j + 12 + esub);
            fma_row(hp, s0, c4, w0, aL[0], aH[0]);
            fma_row(hp, s1, c4, w1, aL[1], aH[1]);
            fma_row(hp, s2, c4, w2, aL[2], aH[2]);
            fma_row(hp, s3, c4, w3, aL[3], aH[3]);
        } else {
            add_row(hp, s0, c4, aL[0], aH[0]);
            add_row(hp, s1, c4, aL[1], aH[1]);
            add_row(hp, s2, c4, aL[2], aH[2]);
            add_row(hp, s3, c4, aL[3], aH[3]);
        }
    }
    for (; j < lim; j += 4) {                  // tail: clamp pads to zero row
        int jj = j + esub;                     // jj <= 63 here
        int sr = __shfl(idx, jj);              // uniform exec
        int s  = (jj < lim) ? sr : n;          // zero row at index n
        if constexpr (SCALE) {
            float w = __shfl(dsv, jj);         // w*0 = 0 on padded rows
            fma_row(hp, s, c4, w, aL[0], aH[0]);
        } else {
            add_row(hp, s, c4, aL[0], aH[0]);
        }
    }
    v2f sL = (aL[0] + aL[1]) + (aL[2] + aL[3]);
    v2f sH = (aH[0] + aH[1]) + (aH[2] + aH[3]);
    float4 a0 = make_float4(sL.x, sL.y, sH.x, sH.y);
    #pragma unroll
    for (int o = 16; o <= 32; o <<= 1) {
        a0.x += __shfl_xor(a0.x, o);
        a0.y += __shfl_xor(a0.y, o);
        a0.z += __shfl_xor(a0.z, o);
        a0.w += __shfl_xor(a0.w, o);
    }
    float4 bb = *(const float4*)(bias + c4);
    float4 o;
    o.x = fmaxf(bb.x + dd * a0.x, 0.f);
    o.y = fmaxf(bb.y + dd * a0.y, 0.f);
    o.z = fmaxf(bb.z + dd * a0.z, 0.f);
    o.w = fmaxf(bb.w + dd * a0.w, 0.f);
    if (!FUSE) {
        if (esub == 0) {
            union { __half2 h[2]; float2 f; } u;
            u.h[0] = __floats2half2_rn(o.x, o.y);
            u.h[1] = __floats2half2_rn(o.z, o.w);
            *(float2*)((__half*)outb + (size_t)d * 64 + c4) = u.f;
        }
    } else {
        const float4* W4 = (const float4*)Wfc;   // row r -> Wfc[r][0..3]
        float4 w0 = W4[c4 + 0], w1 = W4[c4 + 1], w2 = W4[c4 + 2], w3 = W4[c4 + 3];
        float4 p;
        p.x = o.x * w0.x + o.y * w1.x + o.z * w2.x + o.w * w3.x;
        p.y = o.x * w0.y + o.y * w1.y + o.z * w2.y + o.w * w3.y;
        p.z = o.x * w0.z + o.y * w1.z + o.z * w2.z + o.w * w3.z;
        p.w = o.x * w0.w + o.y * w1.w + o.z * w2.w + o.w * w3.w;
        #pragma unroll
        for (int q = 1; q <= 8; q <<= 1) {
            p.x += __shfl_xor(p.x, q);
            p.y += __shfl_xor(p.y, q);
            p.z += __shfl_xor(p.z, q);
            p.w += __shfl_xor(p.w, q);
        }
        if (lane == 0) {
            float4 bf = *(const float4*)bfc;
            float4 r = make_float4(p.x + bf.x, p.y + bf.y, p.z + bf.z, p.w + bf.w);
            ((float4*)outb)[d] = r;
        }
    }
}

static inline size_t align256(size_t x) { return (x + 255) & ~(size_t)255; }

extern "C" void kernel_launch(void* const* d_in, const int* in_sizes, int n_in,
                              void* d_out, int out_size, void* d_ws, size_t ws_size,
                              hipStream_t stream) {
    const float* x   = (const float*)d_in[0];
    const int*   ei  = (const int*)d_in[1];
    const float* W1  = (const float*)d_in[2];
    const float* b1  = (const float*)d_in[3];
    const float* W2  = (const float*)d_in[4];
    const float* b2  = (const float*)d_in[5];
    const float* Wfc = (const float*)d_in[6];
    const float* bfc = (const float*)d_in[7];
    float* out = (float*)d_out;

    int n = in_sizes[0] / 128;   // 100000
    int e = in_sizes[1] / 2;     // 1600000
    const int* src = ei;
    const int* dst = ei + e;

    char* ws = (char*)d_ws;
    size_t p = 0;
    int*      cnt    = (int*)     (ws + p); p = align256(p + (size_t)n * 4);
    int*      bcur   = (int*)     (ws + p); p = align256(p + 512 * 4);
    unsigned* binned = (unsigned*)(ws + p); p = align256(p + (size_t)512 * BCAP * 4);
    int*      slots  = (int*)     (ws + p); p = align256(p + (size_t)n * CAP * 4);
    __half*   hbuf   = (__half*)  (ws + p); p = align256(p + (size_t)(n + 1) * 64 * 2);
    __half*   a1h    = (__half*)  (ws + p);           // n*64 fp16

    int gb  = (n + 127) / 128;       // 782 gemm tiles (last covers row n)
    int nbk = (n + 255) / 256;       // 391 buckets

    // zero bin cursors only (cnt is fully written by k_bucket2), then the
    // fused CSR-bin + gemm1 (bin blocks first; gemm blocks backfill CUs).
    hipMemsetAsync(bcur, 0, 512 * sizeof(int), stream);
    k_bin_gemm1<<<BINB + gb, 256, 0, stream>>>(src, dst, e, bcur, binned,
                                               x, W1, hbuf, n);
    k_bucket2<<<nbk, 256, 0, stream>>>(binned, bcur, n, cnt, slots);

    // layer 1 aggregate: a1 = relu(b1 + ds*(ds*h1[d] + sum ds_s*h1[s]))
    k_gather<false, true><<<(n * 64 + 255) / 256, 256, 0, stream>>>(
        hbuf, slots, cnt, b1, a1h, nullptr, nullptr, n);

    // layer 2: h2' (fp16, MFMA, scaled, reuses hbuf) -> fused final projection
    k_gemm2<<<gb, 256, 0, stream>>>(a1h, W2, cnt, hbuf, n);
    k_gather<true, false><<<(n * 64 + 255) / 256, 256, 0, stream>>>(
        hbuf, slots, cnt, b2, out, Wfc, bfc, n);
}